// Round 2
// baseline (356.977 us; speedup 1.0000x reference)
//
#include <hip/hip_runtime.h>

#define N 8192
#define T 512
#define S 4
#define NCHUNK 4          // chunks per chain
#define WARM 64           // warm-up steps per chunk (psi^64 ~ 5e-20 => exact in fp32)

__device__ __forceinline__ float dot4(float4 a, float4 b) {
    return a.x*b.x + a.y*b.y + a.z*b.z + a.w*b.w;
}

// b[n*T + t] = proj(n,t) + alpha_Y * Y[n,t-1]   (t >= 1)
// b[n*T + 0] = mu_init + proj(n,0)              (= mu0[n])
__global__ __launch_bounds__(256) void k_bias(
        const float* __restrict__ drivers,
        const float* __restrict__ cov,
        const float* __restrict__ Y,
        const float* __restrict__ gamma_w,
        const float* __restrict__ alpha_w,
        const float* __restrict__ alpha_Y_lag,
        const float* __restrict__ mu_init,
        float* __restrict__ bws) {
    int id = blockIdx.x * blockDim.x + threadIdx.x;   // id = n*T + t
    const float4* g4 = (const float4*)gamma_w;
    const float4* a4 = (const float4*)alpha_w;
    float4 g0 = g4[0], g1 = g4[1];
    float4 w0 = a4[0], w1 = a4[1], w2 = a4[2], w3 = a4[3];

    const float4* d4 = (const float4*)drivers + (size_t)id * 2;
    float4 dA = d4[0], dB = d4[1];
    const float4* c4 = (const float4*)cov + (size_t)id * 4;
    float4 cA = c4[0], cB = c4[1], cC = c4[2], cD = c4[3];

    float proj = dot4(dA, g0) + dot4(dB, g1)
               + dot4(cA, w0) + dot4(cB, w1) + dot4(cC, w2) + dot4(cD, w3);

    int t = id & (T - 1);
    float out;
    if (t == 0) {
        out = mu_init[0] + proj;
    } else {
        out = proj + alpha_Y_lag[0] * Y[id - 1];
    }
    bws[id] = out;
}

// One thread per (chunk, s, n): CH=T/NCHUNK steps + WARM warm-up steps.
// tid = ((c*S + s) * N + n)  -> lanes span consecutive n (same s,c per wave).
__global__ __launch_bounds__(256) void k_scan(
        const float* __restrict__ bws,
        const float* __restrict__ eps,
        const float* __restrict__ tilde_psi,
        const float* __restrict__ log_tilde_sigma,
        const float* __restrict__ log_sigma_init,
        float* __restrict__ Zout,
        float* __restrict__ muout,
        float* __restrict__ lvout,
        int writeLv) {
    int tid = blockIdx.x * blockDim.x + threadIdx.x;
    int n  = tid & (N - 1);
    int sc = tid >> 13;                // N = 2^13
    int s  = sc & (S - 1);
    int c  = sc >> 2;                  // S = 4

    const int CH = T / NCHUNK;         // 128 steps per chunk

    float psi   = tilde_psi[0];
    float sigma = expf(log_tilde_sigma[0]);

    size_t chain = ((size_t)s * N + n) * T;
    const float4* e4 = (const float4*)(eps + chain);
    const float4* b4 = (const float4*)(bws + (size_t)n * T);
    float4* z4 = (float4*)(Zout + chain);
    float4* m4 = (float4*)(muout + chain);
    float4* l4 = (float4*)(lvout + chain);

    int v0 = c * (CH / 4);             // first float4 group of this chunk
    float Z;
    int vstart;

    if (c == 0) {
        // exact initial step at t=0
        float sigma0 = expf(log_sigma_init[0]);
        float4 e = e4[0], b = b4[0];
        float4 zo, mo;
        float m;
        m = b.x;           Z = m + sigma0 * e.x; zo.x = Z; mo.x = m;
        m = psi*Z + b.y;   Z = m + sigma  * e.y; zo.y = Z; mo.y = m;
        m = psi*Z + b.z;   Z = m + sigma  * e.z; zo.z = Z; mo.z = m;
        m = psi*Z + b.w;   Z = m + sigma  * e.w; zo.w = Z; mo.w = m;
        z4[0] = zo; m4[0] = mo;
        if (writeLv) {
            float lvv = 2.f * log_tilde_sigma[0];
            float4 lo = make_float4(2.f * log_sigma_init[0], lvv, lvv, lvv);
            l4[0] = lo;
        }
        vstart = 1;
    } else {
        // warm-up: start WARM steps early from Z=0; error ~ psi^(WARM+1) ~ 0
        Z = 0.f;
        #pragma unroll 4
        for (int v = v0 - WARM / 4; v < v0; ++v) {
            float4 e = e4[v], b = b4[v];
            float m;
            m = psi*Z + b.x; Z = m + sigma*e.x;
            m = psi*Z + b.y; Z = m + sigma*e.y;
            m = psi*Z + b.z; Z = m + sigma*e.z;
            m = psi*Z + b.w; Z = m + sigma*e.w;
        }
        vstart = v0;
    }

    float lvv = 2.f * log_tilde_sigma[0];
    float4 lo = make_float4(lvv, lvv, lvv, lvv);
    int vend = v0 + CH / 4;
    #pragma unroll 4
    for (int v = vstart; v < vend; ++v) {
        float4 e = e4[v], b = b4[v];
        float4 zo, mo;
        float m;
        m = psi*Z + b.x; Z = m + sigma*e.x; zo.x = Z; mo.x = m;
        m = psi*Z + b.y; Z = m + sigma*e.y; zo.y = Z; mo.y = m;
        m = psi*Z + b.z; Z = m + sigma*e.z; zo.z = Z; mo.z = m;
        m = psi*Z + b.w; Z = m + sigma*e.w; zo.w = Z; mo.w = m;
        z4[v] = zo; m4[v] = mo;
        if (writeLv) l4[v] = lo;
    }
}

// fallback lv fill (only used if ws_size too small for b scratch)
__global__ __launch_bounds__(256) void k_lv(
        float* __restrict__ lv,
        const float* __restrict__ lts,
        const float* __restrict__ lsi) {
    int i = blockIdx.x * blockDim.x + threadIdx.x;    // float4 index
    float v = 2.0f * lts[0];
    float4 o = make_float4(v, v, v, v);
    if ((i & (T / 4 - 1)) == 0) o.x = 2.0f * lsi[0];
    ((float4*)lv)[i] = o;
}

extern "C" void kernel_launch(void* const* d_in, const int* in_sizes, int n_in,
                              void* d_out, int out_size, void* d_ws, size_t ws_size,
                              hipStream_t stream) {
    const float* drivers   = (const float*)d_in[0];
    const float* cov       = (const float*)d_in[1];
    const float* Y         = (const float*)d_in[2];
    const float* eps       = (const float*)d_in[3];
    const float* tilde_psi = (const float*)d_in[4];
    const float* gamma_w   = (const float*)d_in[5];
    const float* alpha_w   = (const float*)d_in[6];
    const float* aY        = (const float*)d_in[7];
    const float* lts       = (const float*)d_in[8];
    const float* mu_init   = (const float*)d_in[9];
    const float* lsi       = (const float*)d_in[10];

    float* out   = (float*)d_out;
    const size_t SNT = (size_t)S * N * T;
    float* Zout  = out;
    float* muout = out + SNT;
    float* lvout = out + 2 * SNT;

    const size_t bbytes = (size_t)N * T * sizeof(float);
    bool ws_ok = (ws_size >= bbytes);
    float* bws = ws_ok ? (float*)d_ws : lvout;   // observed ws_size ~1 GiB

    k_bias<<<(N * T) / 256, 256, 0, stream>>>(drivers, cov, Y, gamma_w, alpha_w,
                                              aY, mu_init, bws);
    k_scan<<<(NCHUNK * S * N) / 256, 256, 0, stream>>>(
        bws, eps, tilde_psi, lts, lsi, Zout, muout, lvout, ws_ok ? 1 : 0);
    if (!ws_ok) {
        k_lv<<<(SNT / 4) / 256, 256, 0, stream>>>(lvout, lts, lsi);
    }
}

// Round 3
// 154.301 us; speedup vs baseline: 2.3135x; 2.3135x over previous
//
#include <hip/hip_runtime.h>

#define N 8192
#define T 512
#define S 4

__device__ __forceinline__ float dot4(float4 a, float4 b) {
    return a.x*b.x + a.y*b.y + a.z*b.z + a.w*b.w;
}

// One wave per n. Lane l owns t = l*8 .. l*8+7 (contiguous -> coalesced).
// Computes b once, then scans all S samples via weighted wave prefix scan.
__global__ __launch_bounds__(256) void k_fused(
        const float* __restrict__ drivers,
        const float* __restrict__ cov,
        const float* __restrict__ Y,
        const float* __restrict__ eps,
        const float* __restrict__ tilde_psi,
        const float* __restrict__ gamma_w,
        const float* __restrict__ alpha_w,
        const float* __restrict__ alpha_Y_lag,
        const float* __restrict__ log_tilde_sigma,
        const float* __restrict__ mu_init,
        const float* __restrict__ log_sigma_init,
        float* __restrict__ Zout,
        float* __restrict__ muout,
        float* __restrict__ lvout) {
    const int n    = blockIdx.x * (blockDim.x >> 6) + (threadIdx.x >> 6);
    const int lane = threadIdx.x & 63;
    const int t0   = lane * 8;

    const float psi    = tilde_psi[0];
    const float lts    = log_tilde_sigma[0];
    const float lsi    = log_sigma_init[0];
    const float sigma  = expf(lts);
    const float sigma0 = expf(lsi);
    const float aY     = alpha_Y_lag[0];

    const float4* g4 = (const float4*)gamma_w;
    const float4* a4 = (const float4*)alpha_w;
    const float4 g0 = g4[0], g1 = g4[1];
    const float4 w0 = a4[0], w1 = a4[1], w2 = a4[2], w3 = a4[3];

    // psi powers: pj[i] = psi^i ; wd[i] = psi^(8*2^i) for the shfl scan
    float pj[9];
    pj[0] = 1.f;
    #pragma unroll
    for (int i = 1; i <= 8; ++i) pj[i] = pj[i-1] * psi;
    float wd[6];
    wd[0] = pj[8];
    #pragma unroll
    for (int i = 1; i < 6; ++i) wd[i] = wd[i-1] * wd[i-1];

    // ---- b[j] = proj + aY*Y[t-1]  (b[0] at t=0: mu_init + proj) ----
    const size_t ntbase = (size_t)n * T + t0;
    float b[8];
    {
        float proj[8];
        #pragma unroll
        for (int j = 0; j < 8; ++j) {
            const float4* d4 = (const float4*)(drivers + (ntbase + j) * 8);
            const float4* c4 = (const float4*)(cov     + (ntbase + j) * 16);
            float4 dA = d4[0], dB = d4[1];
            float4 cA = c4[0], cB = c4[1], cC = c4[2], cD = c4[3];
            proj[j] = dot4(dA, g0) + dot4(dB, g1)
                    + dot4(cA, w0) + dot4(cB, w1) + dot4(cC, w2) + dot4(cD, w3);
        }
        const float4* y4 = (const float4*)(Y + ntbase);
        float4 yA = y4[0], yB = y4[1];
        float yprev = __shfl_up(yB.w, 1);               // Y[t0-1] from lane-1
        b[0] = (lane == 0) ? (mu_init[0] + proj[0]) : (proj[0] + aY * yprev);
        b[1] = proj[1] + aY * yA.x;
        b[2] = proj[2] + aY * yA.y;
        b[3] = proj[3] + aY * yA.z;
        b[4] = proj[4] + aY * yA.w;
        b[5] = proj[5] + aY * yB.x;
        b[6] = proj[6] + aY * yB.y;
        b[7] = proj[7] + aY * yB.z;
    }

    const float lvv = 2.f * lts;
    const float4 lB = make_float4(lvv, lvv, lvv, lvv);
    const float4 lA = make_float4(lane == 0 ? 2.f * lsi : lvv, lvv, lvv, lvv);

    #pragma unroll
    for (int s = 0; s < S; ++s) {
        const size_t chain = ((size_t)s * N + n) * T + t0;
        const float4* e4 = (const float4*)(eps + chain);
        float4 eA = e4[0], eB = e4[1];
        float e[8] = {eA.x, eA.y, eA.z, eA.w, eB.x, eB.y, eB.z, eB.w};

        // local inclusive scan from zero: z[j] = psi*z[j-1] + (b[j]+sg*e[j])
        float z[8];
        float acc = 0.f;
        #pragma unroll
        for (int j = 0; j < 8; ++j) {
            float sg = (lane == 0 && j == 0) ? sigma0 : sigma;
            acc = psi * acc + (b[j] + sg * e[j]);
            z[j] = acc;
        }

        // wave-level weighted inclusive scan of per-lane carries
        float v = acc;
        #pragma unroll
        for (int i = 0, d = 1; d < 64; d <<= 1, ++i) {
            float up = __shfl_up(v, d);
            v += (lane >= d) ? wd[i] * up : 0.f;
        }
        float Zprev = __shfl_up(v, 1);
        Zprev = (lane == 0) ? 0.f : Zprev;               // Z_{t0-1}

        float Zf[8], mu[8];
        #pragma unroll
        for (int j = 0; j < 8; ++j) {
            Zf[j] = z[j] + pj[j + 1] * Zprev;
            float sg = (lane == 0 && j == 0) ? sigma0 : sigma;
            mu[j] = Zf[j] - sg * e[j];
        }

        float4* z4 = (float4*)(Zout  + chain);
        float4* m4 = (float4*)(muout + chain);
        float4* l4 = (float4*)(lvout + chain);
        z4[0] = make_float4(Zf[0], Zf[1], Zf[2], Zf[3]);
        z4[1] = make_float4(Zf[4], Zf[5], Zf[6], Zf[7]);
        m4[0] = make_float4(mu[0], mu[1], mu[2], mu[3]);
        m4[1] = make_float4(mu[4], mu[5], mu[6], mu[7]);
        l4[0] = lA;
        l4[1] = lB;
    }
}

extern "C" void kernel_launch(void* const* d_in, const int* in_sizes, int n_in,
                              void* d_out, int out_size, void* d_ws, size_t ws_size,
                              hipStream_t stream) {
    const float* drivers   = (const float*)d_in[0];
    const float* cov       = (const float*)d_in[1];
    const float* Y         = (const float*)d_in[2];
    const float* eps       = (const float*)d_in[3];
    const float* tilde_psi = (const float*)d_in[4];
    const float* gamma_w   = (const float*)d_in[5];
    const float* alpha_w   = (const float*)d_in[6];
    const float* aY        = (const float*)d_in[7];
    const float* lts       = (const float*)d_in[8];
    const float* mu_init   = (const float*)d_in[9];
    const float* lsi       = (const float*)d_in[10];

    float* out   = (float*)d_out;
    const size_t SNT = (size_t)S * N * T;
    float* Zout  = out;
    float* muout = out + SNT;
    float* lvout = out + 2 * SNT;

    // one wave per n, 4 waves per block
    k_fused<<<N / 4, 256, 0, stream>>>(drivers, cov, Y, eps, tilde_psi,
                                       gamma_w, alpha_w, aY, lts, mu_init, lsi,
                                       Zout, muout, lvout);
}

// Round 4
// 140.853 us; speedup vs baseline: 2.5344x; 1.0955x over previous
//
#include <hip/hip_runtime.h>

#define N 8192
#define T 512
#define S 4

__device__ __forceinline__ float dot4(float4 a, float4 b) {
    return a.x*b.x + a.y*b.y + a.z*b.z + a.w*b.w;
}
// XOR bank swizzle on float4-chunk index: uniform for strides 1,2,4
__device__ __forceinline__ int swz(int c) { return c ^ ((c >> 3) & 7); }

// One block (256 thr, 4 waves) per n. Stage drivers/cov via LDS (coalesced),
// compute b[t] per thread, then wave w scans sample s=w with a 2-segment
// chunk-interleaved weighted prefix scan (all global I/O wave-contiguous).
__global__ __launch_bounds__(256) void k_fused(
        const float* __restrict__ drivers,
        const float* __restrict__ cov,
        const float* __restrict__ Y,
        const float* __restrict__ eps,
        const float* __restrict__ tilde_psi,
        const float* __restrict__ gamma_w,
        const float* __restrict__ alpha_w,
        const float* __restrict__ alpha_Y_lag,
        const float* __restrict__ log_tilde_sigma,
        const float* __restrict__ mu_init,
        const float* __restrict__ log_sigma_init,
        float* __restrict__ Zout,
        float* __restrict__ muout,
        float* __restrict__ lvout) {
    __shared__ float4 dstage[512];    // 8 KB: 256 rows x 2 chunks (one half)
    __shared__ float4 cstage[1024];   // 16 KB: 256 rows x 4 chunks
    __shared__ float4 b_s4[128];      // 2 KB: b[0..511]
    float* b_s = (float*)b_s4;

    const int tid  = threadIdx.x;
    const int lane = tid & 63;
    const int w    = tid >> 6;        // wave id == sample s
    const int n    = blockIdx.x;

    const float psi    = tilde_psi[0];
    const float lts    = log_tilde_sigma[0];
    const float lsi    = log_sigma_init[0];
    const float sigma  = expf(lts);
    const float sigma0 = expf(lsi);
    const float aY     = alpha_Y_lag[0];
    const float mu0c   = mu_init[0];

    const float4* g4 = (const float4*)gamma_w;
    const float4* a4 = (const float4*)alpha_w;
    const float4 g0 = g4[0], g1 = g4[1];
    const float4 w0 = a4[0], w1 = a4[1], w2 = a4[2], w3 = a4[3];

    // ---- early eps loads (independent of LDS phase; hides HBM latency) ----
    const size_t chain = ((size_t)w * N + n) * (T / 4);   // float4 units
    const float4* e4 = (const float4*)eps + chain;
    const float4 eA = e4[lane];        // segment A: t = 4*lane .. 4*lane+3
    const float4 eB = e4[64 + lane];   // segment B: t = 256+4*lane ..

    // ---- bias phase: two half-rounds of 256 t's ----
    const float4* drv4 = (const float4*)drivers + (size_t)n * (T * 2);
    const float4* cov4 = (const float4*)cov     + (size_t)n * (T * 4);
    const float*  Yrow = Y + (size_t)n * T;

    #pragma unroll
    for (int h = 0; h < 2; ++h) {
        if (h) __syncthreads();                  // protect LDS reuse
        dstage[swz(tid)]       = drv4[h * 512 + tid];
        dstage[swz(tid + 256)] = drv4[h * 512 + 256 + tid];
        #pragma unroll
        for (int k = 0; k < 4; ++k)
            cstage[swz(tid + 256 * k)] = cov4[h * 1024 + tid + 256 * k];
        const int t = h * 256 + tid;
        const float yprev = (t > 0) ? Yrow[t - 1] : 0.f;   // coalesced scalar
        __syncthreads();
        const float4 dA = dstage[swz(2 * tid)];
        const float4 dB = dstage[swz(2 * tid + 1)];
        const float4 cA = cstage[swz(4 * tid)];
        const float4 cB = cstage[swz(4 * tid + 1)];
        const float4 cC = cstage[swz(4 * tid + 2)];
        const float4 cD = cstage[swz(4 * tid + 3)];
        const float proj = dot4(dA, g0) + dot4(dB, g1)
                         + dot4(cA, w0) + dot4(cB, w1)
                         + dot4(cC, w2) + dot4(cD, w3);
        b_s[t] = (t == 0) ? (mu0c + proj) : (proj + aY * yprev);
    }
    __syncthreads();

    // ---- scan phase: wave w handles sample s = w ----
    const float pj1 = psi, pj2 = psi * psi, pj3 = pj2 * psi, pj4 = pj2 * pj2;
    const float wd0 = pj4, wd1 = wd0 * wd0, wd2 = wd1 * wd1,
                wd3 = wd2 * wd2, wd4 = wd3 * wd3, wd5 = wd4 * wd4;
    // p4l = psi^(4*lane)
    float p4l = 1.f;
    {
        float pw = pj4;
        p4l *= (lane & 1)  ? pw : 1.f; pw *= pw;
        p4l *= (lane & 2)  ? pw : 1.f; pw *= pw;
        p4l *= (lane & 4)  ? pw : 1.f; pw *= pw;
        p4l *= (lane & 8)  ? pw : 1.f; pw *= pw;
        p4l *= (lane & 16) ? pw : 1.f; pw *= pw;
        p4l *= (lane & 32) ? pw : 1.f;
    }

    float4* z4 = (float4*)Zout  + chain;
    float4* m4 = (float4*)muout + chain;
    float4* l4 = (float4*)lvout + chain;
    const float lvv = 2.f * lts;

    float Zlast = 0.f;
    #pragma unroll
    for (int seg = 0; seg < 2; ++seg) {
        const float4 e  = seg ? eB : eA;
        const float4 bq = b_s4[seg * 64 + lane];   // stride-1: conflict-free

        const float sg0 = (seg == 0 && lane == 0) ? sigma0 : sigma;
        // local inclusive scan (from zero state)
        const float z0 = bq.x + sg0 * e.x;
        const float z1 = psi * z0 + (bq.y + sigma * e.y);
        const float z2 = psi * z1 + (bq.z + sigma * e.z);
        const float z3 = psi * z2 + (bq.w + sigma * e.w);

        // wave-level weighted inclusive scan of carries (weight psi^4/step)
        float v = z3, up;
        up = __shfl_up(v, 1);  v += (lane >= 1)  ? wd0 * up : 0.f;
        up = __shfl_up(v, 2);  v += (lane >= 2)  ? wd1 * up : 0.f;
        up = __shfl_up(v, 4);  v += (lane >= 4)  ? wd2 * up : 0.f;
        up = __shfl_up(v, 8);  v += (lane >= 8)  ? wd3 * up : 0.f;
        up = __shfl_up(v, 16); v += (lane >= 16) ? wd4 * up : 0.f;
        up = __shfl_up(v, 32); v += (lane >= 32) ? wd5 * up : 0.f;

        float Zprev = __shfl_up(v, 1);
        Zprev = (lane == 0) ? 0.f : Zprev;
        Zprev += p4l * Zlast;                      // bridge from segment A

        const float Z0 = z0 + pj1 * Zprev;
        const float Z1 = z1 + pj2 * Zprev;
        const float Z2 = z2 + pj3 * Zprev;
        const float Z3 = z3 + pj4 * Zprev;

        const float mu0 = Z0 - sg0   * e.x;
        const float mu1 = Z1 - sigma * e.y;
        const float mu2 = Z2 - sigma * e.z;
        const float mu3 = Z3 - sigma * e.w;

        z4[seg * 64 + lane] = make_float4(Z0, Z1, Z2, Z3);
        m4[seg * 64 + lane] = make_float4(mu0, mu1, mu2, mu3);
        l4[seg * 64 + lane] = (seg == 0 && lane == 0)
                            ? make_float4(2.f * lsi, lvv, lvv, lvv)
                            : make_float4(lvv, lvv, lvv, lvv);

        Zlast = __shfl(Z3, 63);                    // Z_255 broadcast
    }
}

extern "C" void kernel_launch(void* const* d_in, const int* in_sizes, int n_in,
                              void* d_out, int out_size, void* d_ws, size_t ws_size,
                              hipStream_t stream) {
    const float* drivers   = (const float*)d_in[0];
    const float* cov       = (const float*)d_in[1];
    const float* Y         = (const float*)d_in[2];
    const float* eps       = (const float*)d_in[3];
    const float* tilde_psi = (const float*)d_in[4];
    const float* gamma_w   = (const float*)d_in[5];
    const float* alpha_w   = (const float*)d_in[6];
    const float* aY        = (const float*)d_in[7];
    const float* lts       = (const float*)d_in[8];
    const float* mu_init   = (const float*)d_in[9];
    const float* lsi       = (const float*)d_in[10];

    float* out   = (float*)d_out;
    const size_t SNT = (size_t)S * N * T;
    float* Zout  = out;
    float* muout = out + SNT;
    float* lvout = out + 2 * SNT;

    k_fused<<<N, 256, 0, stream>>>(drivers, cov, Y, eps, tilde_psi,
                                   gamma_w, alpha_w, aY, lts, mu_init, lsi,
                                   Zout, muout, lvout);
}